// Round 1
// baseline (132.539 us; speedup 1.0000x reference)
//
#include <hip/hip_runtime.h>
#include <math.h>

#define DD 128
#define CC 100
#define MARGIN_F 0.5f
#define EPS_F 1e-6f

// Kernel 1: normalize prototypes (C=100 rows of D=128).
// Outputs: pn[j*128+k] = normalized prototype, cj[j] = ||p_j||^2 - 2*EPS*sum(p_j)
// (both computed on the NORMALIZED row, matching the reference).
__global__ void proto_prep_kernel(const float* __restrict__ p,
                                  float* __restrict__ pn,
                                  float* __restrict__ cj) {
    int j = blockIdx.x;       // one wave (64 threads) per prototype row
    int lane = threadIdx.x;   // 0..63
    float a = p[j * DD + lane];
    float b = p[j * DD + lane + 64];
    float ss = a * a + b * b;
    float s1 = a + b;
#pragma unroll
    for (int off = 32; off > 0; off >>= 1) {
        ss += __shfl_down(ss, off);
        s1 += __shfl_down(s1, off);
    }
    ss = __shfl(ss, 0);
    s1 = __shfl(s1, 0);
    float inv = 1.0f / fmaxf(sqrtf(ss), 1e-12f);
    pn[j * DD + lane] = a * inv;
    pn[j * DD + lane + 64] = b * inv;
    if (lane == 0) {
        float p2 = ss * inv * inv;   // sum(pn^2), ~1
        float sp = s1 * inv;         // sum(pn)
        cj[j] = p2 - 2.0f * EPS_F * sp;
    }
}

// Kernel 2: per-sample normalize + 100 distances + hinge reduction.
// One thread per sample; feature row held in 32 float4 registers.
__global__ __launch_bounds__(256) void proto_triplet_kernel(
        const float* __restrict__ feat,
        const float* __restrict__ pn,
        const float* __restrict__ cj,
        const int* __restrict__ labels,
        float* __restrict__ out,
        int Bn, float scale) {
    int i = blockIdx.x * blockDim.x + threadIdx.x;
    float acc = 0.0f;
    if (i < Bn) {
        const float4* f4 = (const float4*)(feat + (size_t)i * DD);
        float4 fr[32];
        float n2 = 0.0f, s1 = 0.0f;
#pragma unroll
        for (int k = 0; k < 32; ++k) {
            float4 v = f4[k];
            fr[k] = v;
            n2 += v.x * v.x + v.y * v.y + v.z * v.z + v.w * v.w;
            s1 += v.x + v.y + v.z + v.w;
        }
        float inv = 1.0f / fmaxf(sqrtf(n2), 1e-12f);
#pragma unroll
        for (int k = 0; k < 32; ++k) {
            fr[k].x *= inv; fr[k].y *= inv; fr[k].z *= inv; fr[k].w *= inv;
        }
        float f2 = n2 * inv * inv;  // sum(fn^2), ~1
        float sf = s1 * inv;        // sum(fn)
        float cf = f2 + 2.0f * EPS_F * sf + (float)DD * (EPS_F * EPS_F);
        int lab = labels[i];
        const float4* p4 = (const float4*)pn;

        // d_pos: distance to the labeled prototype (divergent gather; hot in L1/L2)
        float dpos;
        {
            const float4* pj = p4 + (size_t)lab * 32;
            float ax = 0.f, ay = 0.f, az = 0.f, aw = 0.f;
#pragma unroll
            for (int k = 0; k < 32; ++k) {
                float4 pv = pj[k];
                ax = fmaf(fr[k].x, pv.x, ax);
                ay = fmaf(fr[k].y, pv.y, ay);
                az = fmaf(fr[k].z, pv.z, az);
                aw = fmaf(fr[k].w, pv.w, aw);
            }
            float dot = (ax + ay) + (az + aw);
            float d2 = cf + cj[lab] - 2.0f * dot;
            dpos = sqrtf(fmaxf(d2, 1e-12f));
        }

        // loop over all C prototypes; label term contributes exactly MARGIN, subtracted after
        float hsum = 0.0f;
#pragma unroll 1
        for (int j = 0; j < CC; ++j) {
            const float4* pj = p4 + (size_t)j * 32;
            float ax = 0.f, ay = 0.f, az = 0.f, aw = 0.f;
#pragma unroll
            for (int k = 0; k < 32; ++k) {
                float4 pv = pj[k];
                ax = fmaf(fr[k].x, pv.x, ax);
                ay = fmaf(fr[k].y, pv.y, ay);
                az = fmaf(fr[k].z, pv.z, az);
                aw = fmaf(fr[k].w, pv.w, aw);
            }
            float dot = (ax + ay) + (az + aw);
            float d2 = cf + cj[j] - 2.0f * dot;
            float dj = sqrtf(fmaxf(d2, 1e-12f));
            hsum += fmaxf(dpos - dj + MARGIN_F, 0.0f);
        }
        acc = (hsum - MARGIN_F) * scale;
    }

    // block reduction -> one atomic per block
    __shared__ float red[256];
    red[threadIdx.x] = acc;
    __syncthreads();
#pragma unroll
    for (int s = 128; s > 0; s >>= 1) {
        if (threadIdx.x < s) red[threadIdx.x] += red[threadIdx.x + s];
        __syncthreads();
    }
    if (threadIdx.x == 0) atomicAdd(out, red[0]);
}

extern "C" void kernel_launch(void* const* d_in, const int* in_sizes, int n_in,
                              void* d_out, int out_size, void* d_ws, size_t ws_size,
                              hipStream_t stream) {
    const float* feat   = (const float*)d_in[0];
    const float* prot   = (const float*)d_in[1];
    const int*   labels = (const int*)d_in[2];
    float* out = (float*)d_out;
    int Bn = in_sizes[0] / DD;

    float* pn = (float*)d_ws;          // 100*128 floats
    float* cj = pn + CC * DD;          // 100 floats

    hipMemsetAsync(d_out, 0, sizeof(float), stream);
    proto_prep_kernel<<<CC, 64, 0, stream>>>(prot, pn, cj);

    int blocks = (Bn + 255) / 256;
    float scale = 1.0f / ((float)Bn * (float)(CC - 1));
    proto_triplet_kernel<<<blocks, 256, 0, stream>>>(feat, pn, cj, labels, out, Bn, scale);
}

// Round 2
// 93.803 us; speedup vs baseline: 1.4129x; 1.4129x over previous
//
#include <hip/hip_runtime.h>
#include <hip/hip_bf16.h>
#include <math.h>

#define DD 128
#define CC 100
#define NPAD 112          // 7 tiles of 16
#define NT 7
#define MARGIN_F 0.5f
#define EPS_F 1e-6f
#define BROWS 128         // rows per block
#define WROWS 32          // rows per wave (2 M-tiles of 16)

typedef __attribute__((ext_vector_type(8))) short bf16x8;
typedef __attribute__((ext_vector_type(4))) float f32x4;

__device__ __forceinline__ short f2bf(float x) {
    __hip_bfloat16 h = __float2bfloat16(x);
    return *reinterpret_cast<short*>(&h);
}

// prep1: per-prototype norm -> inv_norm[j], cj[j] = ||pn||^2 - 2*EPS*sum(pn).
// j in [100,112): cj = 1e9 (pad kills hinge), inv unused.
__global__ void prep1_kernel(const float* __restrict__ p,
                             float* __restrict__ inv_out,
                             float* __restrict__ cj) {
    int j = blockIdx.x, lane = threadIdx.x;
    if (j >= CC) { if (lane == 0) cj[j] = 1e9f; return; }
    float a = p[j * DD + lane];
    float b = p[j * DD + lane + 64];
    float ss = a * a + b * b;
    float s1 = a + b;
#pragma unroll
    for (int off = 1; off < 64; off <<= 1) {
        ss += __shfl_xor(ss, off);
        s1 += __shfl_xor(s1, off);
    }
    float inv = 1.0f / fmaxf(sqrtf(ss), 1e-12f);
    if (lane == 0) {
        inv_out[j] = inv;
        cj[j] = ss * inv * inv - 2.0f * EPS_F * (s1 * inv);
    }
}

// prep2: write normalized prototypes in B-fragment-major order.
// fragment f = t*4+kk (28 frags); lane l holds n = t*16+(l&15),
// k = kk*32+(l>>4)*8 + j (j=0..7). pnb[f*64 + l] = 8 bf16 (16B).
__global__ void prep2_kernel(const float* __restrict__ p,
                             const float* __restrict__ inv_in,
                             bf16x8* __restrict__ pnb) {
    int f = blockIdx.x, lane = threadIdx.x;
    int t = f >> 2, kk = f & 3;
    int n = t * 16 + (lane & 15);
    int k0 = kk * 32 + (lane >> 4) * 8;
    bf16x8 o;
    if (n < CC) {
        float inv = inv_in[n];
        const float* row = p + n * DD + k0;
#pragma unroll
        for (int j = 0; j < 8; ++j) o[j] = f2bf(row[j] * inv);
    } else {
#pragma unroll
        for (int j = 0; j < 8; ++j) o[j] = 0;
    }
    pnb[f * 64 + lane] = o;
}

// main: 256 threads = 4 waves; 128 rows/block, 32 rows/wave.
__global__ __launch_bounds__(256) void proto_main_kernel(
        const float* __restrict__ feat,
        const bf16x8* __restrict__ pnb,
        const float* __restrict__ cj,
        const int* __restrict__ labels,
        float* __restrict__ out,
        int Bn, float scale) {
    const int w = threadIdx.x >> 6, lane = threadIdx.x & 63;
    const int g = lane >> 4, m = lane & 15;
    const long wb = (long)blockIdx.x * BROWS + w * WROWS;

    __shared__ float cfs[4][32];
    __shared__ int   labs[4][32];
    __shared__ float dposs[4][32];
    __shared__ float cjs[NPAD];
    __shared__ float red[256];

    if (threadIdx.x < NPAD) cjs[threadIdx.x] = cj[threadIdx.x];

    // ---- load + normalize features into A fragments (registers only) ----
    // lane l, mtile mt: row = wb + mt*16 + m ; k = kk*32 + g*8 .. +8
    bf16x8 afr[2][4];
#pragma unroll
    for (int mt = 0; mt < 2; ++mt) {
        long row = wb + mt * 16 + m;
        long rs = row < Bn ? row : (long)(Bn - 1);
        const float4* fp = (const float4*)(feat + rs * DD);
        float4 v[8];
        float ss = 0.0f, s1 = 0.0f;
#pragma unroll
        for (int kk = 0; kk < 4; ++kk) {
            float4 a = fp[kk * 8 + g * 2];
            float4 b = fp[kk * 8 + g * 2 + 1];
            v[kk * 2] = a; v[kk * 2 + 1] = b;
            ss += a.x*a.x + a.y*a.y + a.z*a.z + a.w*a.w
                + b.x*b.x + b.y*b.y + b.z*b.z + b.w*b.w;
            s1 += a.x + a.y + a.z + a.w + b.x + b.y + b.z + b.w;
        }
        // full row sums live across the 4 g-groups (lane ^ 16, lane ^ 32)
        ss += __shfl_xor(ss, 16); ss += __shfl_xor(ss, 32);
        s1 += __shfl_xor(s1, 16); s1 += __shfl_xor(s1, 32);
        float inv = 1.0f / fmaxf(sqrtf(ss), 1e-12f);
        float cf = ss * inv * inv + 2.0f * EPS_F * (s1 * inv)
                 + (float)DD * (EPS_F * EPS_F);
#pragma unroll
        for (int kk = 0; kk < 4; ++kk) {
            float4 a = v[kk * 2], b = v[kk * 2 + 1];
            bf16x8 fr;
            fr[0] = f2bf(a.x * inv); fr[1] = f2bf(a.y * inv);
            fr[2] = f2bf(a.z * inv); fr[3] = f2bf(a.w * inv);
            fr[4] = f2bf(b.x * inv); fr[5] = f2bf(b.y * inv);
            fr[6] = f2bf(b.z * inv); fr[7] = f2bf(b.w * inv);
            afr[mt][kk] = fr;
        }
        if (g == 0) {
            cfs[w][mt * 16 + m] = cf;
            labs[w][mt * 16 + m] = (row < Bn) ? labels[rs] : -999;
        }
    }
    __syncthreads();

    // ---- MFMA: dot[32 rows][112 protos] ----
    f32x4 acc[2][NT];
#pragma unroll
    for (int mt = 0; mt < 2; ++mt)
#pragma unroll
        for (int t = 0; t < NT; ++t) acc[mt][t] = (f32x4)0.0f;

#pragma unroll
    for (int t = 0; t < NT; ++t) {
        bf16x8 bfr[4];
#pragma unroll
        for (int kk = 0; kk < 4; ++kk) bfr[kk] = pnb[(t * 4 + kk) * 64 + lane];
#pragma unroll
        for (int kk = 0; kk < 4; ++kk) {
            acc[0][t] = __builtin_amdgcn_mfma_f32_16x16x32_bf16(
                afr[0][kk], bfr[kk], acc[0][t], 0, 0, 0);
            acc[1][t] = __builtin_amdgcn_mfma_f32_16x16x32_bf16(
                afr[1][kk], bfr[kk], acc[1][t], 0, 0, 0);
        }
    }

    // ---- epilogue. C/D layout: col n = t*16 + m, row = mt*16 + g*4 + r ----
    // pass 1: positive distance per row
#pragma unroll
    for (int mt = 0; mt < 2; ++mt)
#pragma unroll
        for (int t = 0; t < NT; ++t)
#pragma unroll
            for (int r = 0; r < 4; ++r) {
                int rowl = mt * 16 + g * 4 + r;
                int n = t * 16 + m;
                if (labs[w][rowl] == n) {
                    float d2 = cfs[w][rowl] + cjs[n] - 2.0f * acc[mt][t][r];
                    dposs[w][rowl] = sqrtf(fmaxf(d2, 1e-12f));
                }
            }
    __syncthreads();

    // pass 2: hinge sum over negatives
    float hsum = 0.0f;
#pragma unroll
    for (int mt = 0; mt < 2; ++mt)
#pragma unroll
        for (int t = 0; t < NT; ++t)
#pragma unroll
            for (int r = 0; r < 4; ++r) {
                int rowl = mt * 16 + g * 4 + r;
                int n = t * 16 + m;
                float d2 = cfs[w][rowl] + cjs[n] - 2.0f * acc[mt][t][r];
                float dist = sqrtf(fmaxf(d2, 1e-12f));
                float h = fmaxf(dposs[w][rowl] - dist + MARGIN_F, 0.0f);
                bool ok = (n != labs[w][rowl]) && (wb + rowl < (long)Bn);
                hsum += ok ? h : 0.0f;
            }

    // ---- block reduce -> one atomic ----
    red[threadIdx.x] = hsum;
    __syncthreads();
#pragma unroll
    for (int s = 128; s > 0; s >>= 1) {
        if (threadIdx.x < s) red[threadIdx.x] += red[threadIdx.x + s];
        __syncthreads();
    }
    if (threadIdx.x == 0) atomicAdd(out, red[0] * scale);
}

extern "C" void kernel_launch(void* const* d_in, const int* in_sizes, int n_in,
                              void* d_out, int out_size, void* d_ws, size_t ws_size,
                              hipStream_t stream) {
    const float* feat   = (const float*)d_in[0];
    const float* prot   = (const float*)d_in[1];
    const int*   labels = (const int*)d_in[2];
    float* out = (float*)d_out;
    int Bn = in_sizes[0] / DD;

    bf16x8* pnb = (bf16x8*)d_ws;                       // 28 frags * 64 * 16B = 28672 B
    float* cjw  = (float*)((char*)d_ws + 28 * 64 * 16);
    float* invw = cjw + NPAD;

    hipMemsetAsync(d_out, 0, sizeof(float), stream);
    prep1_kernel<<<NPAD, 64, 0, stream>>>(prot, invw, cjw);
    prep2_kernel<<<28, 64, 0, stream>>>(prot, invw, pnb);

    int blocks = (Bn + BROWS - 1) / BROWS;
    float scale = 1.0f / ((float)Bn * (float)(CC - 1));
    proto_main_kernel<<<blocks, 256, 0, stream>>>(feat, pnb, cjw, labels, out, Bn, scale);
}

// Round 3
// 55.417 us; speedup vs baseline: 2.3917x; 1.6927x over previous
//
#include <hip/hip_runtime.h>
#include <hip/hip_bf16.h>
#include <math.h>

#define DD 128
#define CC 100
#define NPAD 112          // 7 tiles of 16
#define NT 7
#define MARGIN_F 0.5f
#define EPS_F 1e-6f
#define BROWS 128         // rows per block (4 waves x 32 rows)

typedef __attribute__((ext_vector_type(8))) short bf16x8;
typedef __attribute__((ext_vector_type(4))) float f32x4;

__device__ __forceinline__ float fsqrt_f(float x) { return __builtin_amdgcn_sqrtf(x); }
__device__ __forceinline__ float frcp_f(float x)  { return __builtin_amdgcn_rcpf(x); }

__device__ __forceinline__ short f2bf(float x) {
    __hip_bfloat16 h = __float2bfloat16(x);
    return *reinterpret_cast<short*>(&h);
}

// prep1: per-prototype norm -> inv_norm[j], cj[j] = ||pn||^2 - 2*EPS*sum(pn).
// j in [100,112): cj = 1e9 (pad kills hinge). Block 0 also initializes out
// to -MARGIN/(C-1) (compensates the label column contributing exactly MARGIN).
__global__ void prep1_kernel(const float* __restrict__ p,
                             float* __restrict__ inv_out,
                             float* __restrict__ cj,
                             float* __restrict__ out) {
    int j = blockIdx.x, lane = threadIdx.x;
    if (j == 0 && lane == 0) out[0] = -MARGIN_F / (float)(CC - 1);
    if (j >= CC) { if (lane == 0) cj[j] = 1e9f; return; }
    float a = p[j * DD + lane];
    float b = p[j * DD + lane + 64];
    float ss = a * a + b * b;
    float s1 = a + b;
#pragma unroll
    for (int off = 1; off < 64; off <<= 1) {
        ss += __shfl_xor(ss, off);
        s1 += __shfl_xor(s1, off);
    }
    float inv = 1.0f / fmaxf(sqrtf(ss), 1e-12f);
    if (lane == 0) {
        inv_out[j] = inv;
        cj[j] = ss * inv * inv - 2.0f * EPS_F * (s1 * inv);
    }
}

// prep2: normalized prototypes in B-fragment-major order.
// fragment f = t*4+kk; lane l holds n = t*16+(l&15), k = kk*32+(l>>4)*8+j.
__global__ void prep2_kernel(const float* __restrict__ p,
                             const float* __restrict__ inv_in,
                             bf16x8* __restrict__ pnb) {
    int f = blockIdx.x, lane = threadIdx.x;
    int t = f >> 2, kk = f & 3;
    int n = t * 16 + (lane & 15);
    int k0 = kk * 32 + (lane >> 4) * 8;
    bf16x8 o;
    if (n < CC) {
        float inv = inv_in[n];
        const float* row = p + n * DD + k0;
#pragma unroll
        for (int j = 0; j < 8; ++j) o[j] = f2bf(row[j] * inv);
    } else {
#pragma unroll
        for (int j = 0; j < 8; ++j) o[j] = 0;
    }
    pnb[f * 64 + lane] = o;
}

// main: 256 threads = 4 waves; 32 rows/wave; barrier count = 1 (final reduce).
__global__ __launch_bounds__(256) void proto_main_kernel(
        const float* __restrict__ feat,
        const bf16x8* __restrict__ pnb,
        const float* __restrict__ cj,
        const int* __restrict__ labels,
        float* __restrict__ out,
        int Bn, float scale) {
    const int lane = threadIdx.x & 63;
    const int w = threadIdx.x >> 6;
    const int g = lane >> 4, m = lane & 15;
    const long wb = (long)blockIdx.x * BROWS + w * 32;

    // ---- load features (raw), row stats, convert raw -> bf16 fragments ----
    bf16x8 afr[2][4];
    float cfv[2], m2iv[2];
    int labv[2];
#pragma unroll
    for (int mt = 0; mt < 2; ++mt) {
        long row = wb + mt * 16 + m;
        long rs = row < Bn ? row : (long)(Bn - 1);
        const float4* fp = (const float4*)(feat + rs * DD);
        float4 va[8];
        float ss = 0.f, s1 = 0.f;
#pragma unroll
        for (int kk = 0; kk < 4; ++kk) {
            float4 a = fp[kk * 8 + g * 2];
            float4 b = fp[kk * 8 + g * 2 + 1];
            va[kk * 2] = a; va[kk * 2 + 1] = b;
            ss += a.x*a.x + a.y*a.y + a.z*a.z + a.w*a.w
                + b.x*b.x + b.y*b.y + b.z*b.z + b.w*b.w;
            s1 += a.x + a.y + a.z + a.w + b.x + b.y + b.z + b.w;
        }
        ss += __shfl_xor(ss, 16); ss += __shfl_xor(ss, 32);
        s1 += __shfl_xor(s1, 16); s1 += __shfl_xor(s1, 32);
        float inv = frcp_f(fmaxf(fsqrt_f(ss), 1e-12f));
        cfv[mt] = ss * inv * inv + 2.0f * EPS_F * (s1 * inv)
                + (float)DD * (EPS_F * EPS_F);
        m2iv[mt] = -2.0f * inv;
        labv[mt] = (int)labels[rs];
#pragma unroll
        for (int kk = 0; kk < 4; ++kk) {
            float4 a = va[kk * 2], b = va[kk * 2 + 1];
            union { bf16x8 v; __hip_bfloat162 h[4]; } u;
            u.h[0] = __float22bfloat162_rn(make_float2(a.x, a.y));
            u.h[1] = __float22bfloat162_rn(make_float2(a.z, a.w));
            u.h[2] = __float22bfloat162_rn(make_float2(b.x, b.y));
            u.h[3] = __float22bfloat162_rn(make_float2(b.z, b.w));
            afr[mt][kk] = u.v;
        }
    }

    // per-lane cj for my 7 columns (L1-resident broadcast)
    float cjr[NT];
#pragma unroll
    for (int t = 0; t < NT; ++t) cjr[t] = cj[t * 16 + m];

    // ---- MFMA: raw-f dot pn, [32 rows][112 cols] ----
    f32x4 acc[2][NT];
#pragma unroll
    for (int mt = 0; mt < 2; ++mt)
#pragma unroll
        for (int t = 0; t < NT; ++t) acc[mt][t] = (f32x4)0.f;

#pragma unroll
    for (int t = 0; t < NT; ++t) {
        bf16x8 bfr[4];
#pragma unroll
        for (int kk = 0; kk < 4; ++kk) bfr[kk] = pnb[(t * 4 + kk) * 64 + lane];
#pragma unroll
        for (int kk = 0; kk < 4; ++kk) {
            acc[0][t] = __builtin_amdgcn_mfma_f32_16x16x32_bf16(
                afr[0][kk], bfr[kk], acc[0][t], 0, 0, 0);
            acc[1][t] = __builtin_amdgcn_mfma_f32_16x16x32_bf16(
                afr[1][kk], bfr[kk], acc[1][t], 0, 0, 0);
        }
    }

    // ---- per-row scalars for MY output rows (g*4+r) via in-wave bpermute ----
    // lanes 0..15 hold row (mt*16 + m) stats; row q=g*4+r < 16 -> src lane q.
    float cf_r[2][4], m2i_r[2][4];
    int lab_r[2][4];
#pragma unroll
    for (int mt = 0; mt < 2; ++mt)
#pragma unroll
        for (int r = 0; r < 4; ++r) {
            int addr = (g * 4 + r) << 2;
            cf_r[mt][r]  = __int_as_float(__builtin_amdgcn_ds_bpermute(addr, __float_as_int(cfv[mt])));
            m2i_r[mt][r] = __int_as_float(__builtin_amdgcn_ds_bpermute(addr, __float_as_int(m2iv[mt])));
            lab_r[mt][r] = __builtin_amdgcn_ds_bpermute(addr, labv[mt]);
        }

    // ---- pass 1: dist (in-place over acc) + select label-column dist ----
    float dsel[2][4] = {{0.f,0.f,0.f,0.f},{0.f,0.f,0.f,0.f}};
#pragma unroll
    for (int mt = 0; mt < 2; ++mt)
#pragma unroll
        for (int t = 0; t < NT; ++t) {
            int col = t * 16 + m;
#pragma unroll
            for (int r = 0; r < 4; ++r) {
                float d2 = fmaf(acc[mt][t][r], m2i_r[mt][r], cf_r[mt][r] + cjr[t]);
                float dist = fsqrt_f(fmaxf(d2, 1e-12f));
                acc[mt][t][r] = dist;
                dsel[mt][r] = (lab_r[mt][r] == col) ? dist : dsel[mt][r];
            }
        }

    // ---- d_pos broadcast within the 16-lane group (src lane = g*16 + (lab&15)) ----
    float hb[2][4];
#pragma unroll
    for (int mt = 0; mt < 2; ++mt)
#pragma unroll
        for (int r = 0; r < 4; ++r) {
            int sl = ((g << 4) + (lab_r[mt][r] & 15)) << 2;
            float dp = __int_as_float(__builtin_amdgcn_ds_bpermute(sl, __float_as_int(dsel[mt][r])));
            long row = wb + mt * 16 + g * 4 + r;
            hb[mt][r] = (row < (long)Bn) ? (dp + MARGIN_F) : -1e30f;
        }

    // ---- pass 2: hinge accumulate (label col contributes MARGIN; pads 0) ----
    float hsum = 0.f;
#pragma unroll
    for (int mt = 0; mt < 2; ++mt)
#pragma unroll
        for (int t = 0; t < NT; ++t)
#pragma unroll
            for (int r = 0; r < 4; ++r)
                hsum += fmaxf(hb[mt][r] - acc[mt][t][r], 0.f);

    // ---- wave reduce + one barrier + one atomic per block ----
#pragma unroll
    for (int off = 32; off > 0; off >>= 1) hsum += __shfl_xor(hsum, off);
    __shared__ float red[4];
    if (lane == 0) red[w] = hsum;
    __syncthreads();
    if (threadIdx.x == 0)
        atomicAdd(out, (red[0] + red[1] + red[2] + red[3]) * scale);
}

extern "C" void kernel_launch(void* const* d_in, const int* in_sizes, int n_in,
                              void* d_out, int out_size, void* d_ws, size_t ws_size,
                              hipStream_t stream) {
    const float* feat   = (const float*)d_in[0];
    const float* prot   = (const float*)d_in[1];
    const int*   labels = (const int*)d_in[2];
    float* out = (float*)d_out;
    int Bn = in_sizes[0] / DD;

    bf16x8* pnb = (bf16x8*)d_ws;                       // 28*64*16B = 28672 B
    float* cjw  = (float*)((char*)d_ws + 28 * 64 * 16);
    float* invw = cjw + NPAD;

    prep1_kernel<<<NPAD, 64, 0, stream>>>(prot, invw, cjw, out);
    prep2_kernel<<<28, 64, 0, stream>>>(prot, invw, pnb);

    int blocks = (Bn + BROWS - 1) / BROWS;
    float scale = 1.0f / ((float)Bn * (float)(CC - 1));
    proto_main_kernel<<<blocks, 256, 0, stream>>>(feat, pnb, cjw, labels, out, Bn, scale);
}